// Round 10
// baseline (113.568 us; speedup 1.0000x reference)
//
#include <hip/hip_runtime.h>
#include <hip/hip_bf16.h>

typedef __attribute__((ext_vector_type(8)))  short short8;
typedef __attribute__((ext_vector_type(4)))  float f32x4;
typedef __attribute__((ext_vector_type(16))) float f32x16;

#define NR 256
#define CC 256

__device__ __forceinline__ unsigned short f2bf(float x) {
    union { float f; unsigned int u; } v; v.f = x;
    unsigned int r = v.u + 0x7FFFu + ((v.u >> 16) & 1u);
    return (unsigned short)(r >> 16);
}

__device__ __forceinline__ unsigned int pk2bf(float a, float b) {
    __hip_bfloat162 h = __float22bfloat162_rn(make_float2(a, b));
    union { __hip_bfloat162 h; unsigned int u; } cv; cv.h = h;
    return cv.u;
}

// ---------------- setup: qp (bx<16) | wvp_pack (bx<81) | mlp pack (else) ----------------
__global__ __launch_bounds__(256) void setup_kernel(
    const float* __restrict__ Q, const float* __restrict__ Wq, float* __restrict__ Qpp,
    const float* __restrict__ Wv, unsigned short* __restrict__ wvp,
    const float* __restrict__ W01, const float* __restrict__ W1,
    const float* __restrict__ W02, const float* __restrict__ W2,
    unsigned short* __restrict__ wpa, unsigned short* __restrict__ wpb)
{
    __shared__ float tile[32][260];
    __shared__ float qs[256];
    const int bx = blockIdx.x;
    const int tid = threadIdx.x;

    if (bx < 16) {                       // ---- Qpp[ksl][b][n] = partial Q @ Wq
        int ksl = bx & 3, b = bx >> 2;
        qs[tid] = Q[b * 1024 + ksl * 256 + tid];
        __syncthreads();
        float acc = 0.f;
        #pragma unroll 4
        for (int d = 0; d < 256; ++d) acc += qs[d] * Wq[(size_t)(ksl * 256 + d) * 256 + tid];
        Qpp[(ksl * 4 + b) * 256 + tid] = acc;
    } else if (bx < 81) {                // ---- Wv -> 16x16x32 B-frag layout, K pad 2080
        int ks = bx - 16;                // 0..64
        for (int idx = tid; idx < 32 * 256; idx += 256) {
            int cr = idx >> 8, n = idx & 255;
            int c = ks * 32 + cr;
            tile[cr][n] = (c < 2056) ? Wv[(size_t)c * 256 + n] : 0.f;
        }
        __syncthreads();
        #pragma unroll
        for (int q = 0; q < 4; ++q) {
            int t2 = tid * 4 + q;
            int nt = t2 >> 6, l = t2 & 63;
            int gg = l >> 4, jj = l & 15;
            short8 s;
            #pragma unroll
            for (int e = 0; e < 8; ++e)
                s[e] = (short)f2bf(tile[gg * 8 + e][nt * 16 + jj]);
            *(short8*)&wvp[((size_t)(ks * 16 + nt) * 64 + l) * 8] = s;
        }
    } else {                             // ---- MLP weights -> 32x32x16 A-frag layout
        int t = (bx - 81) * 256 + tid;   // < 81920
        if (t < 65536) {
            int e = t & 7, l = (t >> 3) & 63, ks = (t >> 9) & 15, nt = (t >> 13) & 3, br = (t >> 15) & 1;
            int cc = ks * 16 + (l >> 5) * 8 + e;
            int n = nt * 32 + (l & 31);
            const float* W = br ? W1 : W01;
            wpa[t] = f2bf(W[cc * 128 + n]);
        } else {
            int t2 = t - 65536;          // < 16384
            int e = t2 & 7, l = (t2 >> 3) & 63, ks = (t2 >> 9) & 7, nt = (t2 >> 12) & 1, br = (t2 >> 13) & 1;
            int cc = ks * 16 + (l >> 5) * 8 + e;
            int n = nt * 32 + (l & 31);
            const float* W = br ? W2 : W02;
            wpb[t2] = f2bf(W[cc * 64 + n]);
        }
    }
}

// ---------------- Xp = concat(X, X[:,:,:4]) @ Wv + bv + bq + Qp  (MFMA, 8-wave split-K) ----------------
__global__ __launch_bounds__(512) void xp_kernel(
    const float* __restrict__ X, const unsigned short* __restrict__ wvp,
    const float* __restrict__ bv, const float* __restrict__ bq,
    const float* __restrict__ Qpp, float* __restrict__ Xp)
{
    __shared__ f32x4 red[8][2][65];
    const int tid = threadIdx.x;
    const int w = tid >> 6;           // 0..7
    const int lane = tid & 63;
    const int g = lane >> 4, j16 = lane & 15;
    const int mt = blockIdx.x;        // 16-row tile
    const int bn = blockIdx.y;        // 32-col tile (0..7)
    const int b  = blockIdx.z;

    const int i0 = mt * 16;
    const int n0 = bn * 32;
    const float* xrow = X + ((size_t)(b * NR) + (i0 + j16)) * 2052;

    f32x4 acc[2] = {};

    for (int ks = w; ks < 64; ks += 8) {
        const int c0 = ks * 32 + g * 8;
        float4 xa = *(const float4*)(xrow + c0);
        float4 xb = *(const float4*)(xrow + c0 + 4);
        union { short8 s; unsigned int u[4]; } af;
        af.u[0] = pk2bf(xa.x, xa.y);
        af.u[1] = pk2bf(xa.z, xa.w);
        af.u[2] = pk2bf(xb.x, xb.y);
        af.u[3] = pk2bf(xb.z, xb.w);
        #pragma unroll
        for (int nt = 0; nt < 2; ++nt) {
            short8 bf = ((const short8*)wvp)[(size_t)(ks * 16 + bn * 2 + nt) * 64 + lane];
            acc[nt] = __builtin_amdgcn_mfma_f32_16x16x32_bf16(af.s, bf, acc[nt], 0, 0, 0);
        }
    }
    if (w == 0) {  // ks = 64 tail: c 2048..2079 (c>=2056 zero-weighted)
        float xv[8];
        #pragma unroll
        for (int e = 0; e < 8; ++e) {
            int q = g * 8 + e;
            int csrc = (q < 4) ? (2048 + q) : (q - 4);
            xv[e] = xrow[csrc];
        }
        union { short8 s; unsigned int u[4]; } af;
        af.u[0] = pk2bf(xv[0], xv[1]);
        af.u[1] = pk2bf(xv[2], xv[3]);
        af.u[2] = pk2bf(xv[4], xv[5]);
        af.u[3] = pk2bf(xv[6], xv[7]);
        #pragma unroll
        for (int nt = 0; nt < 2; ++nt) {
            short8 bf = ((const short8*)wvp)[(size_t)(64 * 16 + bn * 2 + nt) * 64 + lane];
            acc[nt] = __builtin_amdgcn_mfma_f32_16x16x32_bf16(af.s, bf, acc[nt], 0, 0, 0);
        }
    }
    #pragma unroll
    for (int nt = 0; nt < 2; ++nt) red[w][nt][lane] = acc[nt];
    __syncthreads();

    {   // 512 threads, one output each: 16 rows x 32 cols
        int nt  = tid >> 8;              // 0..1
        int rem = tid & 255;
        int l   = rem & 63;
        int reg = (rem >> 6) & 3;
        float r = 0.f;
        #pragma unroll
        for (int ww = 0; ww < 8; ++ww) r += red[ww][nt][l][reg];
        int gg = l >> 4, jj = l & 15;
        int n = n0 + nt * 16 + jj;
        float base = bv[n] + bq[n] + Qpp[b * 256 + n] + Qpp[(4 + b) * 256 + n]
                   + Qpp[(8 + b) * 256 + n] + Qpp[(12 + b) * 256 + n];
        int row = i0 + gg * 4 + reg;
        Xp[((b * NR) + row) * CC + n] = r + base;
    }
}

// ---------------- fused 3-layer MLP over pairs: 8-wave, all-LDS, FUSED jt-pair ----------------
// block = (b, br, it8 in [0,32), jt-pair (jtA, jtB=jtA+1)). Both tiles' B-fragments live in
// registers; every weight fragment read from LDS feeds TWO MFMAs (tile A + B) in L1 and L2
// -> LDS weight traffic halves vs r9 (the measured bottleneck: 8 waves x 2 jt x 80KB
// lane-indexed reads saturated the DS pipe while MFMA sat at 13%).
// t-loop unroll(1) caps register pressure: bfr 128 + acc1 32 + acc2 64 + temps < 256 cap.
// __launch_bounds__(512,1): VGPR cap 256 (empirical: smaller caps spilled in r3/r6).
__global__ __launch_bounds__(512, 1) void pairs_kernel(
    const float* __restrict__ Xp,
    const unsigned short* __restrict__ wpa,
    const unsigned short* __restrict__ wpb,
    const float* __restrict__ b01, const float* __restrict__ b02,
    const float* __restrict__ b03,
    const float* __restrict__ b1,  const float* __restrict__ b2,
    const float* __restrict__ b3,
    const float* __restrict__ W03, const float* __restrict__ W3,
    float* __restrict__ colpart, float* __restrict__ rowpart)
{
    __shared__ __align__(16) unsigned short lds_wa[32768];   // 64 KB: FULL W1 frags (this branch)
    __shared__ __align__(16) unsigned short lds_wb[8192];    // 16 KB: FULL W2 frags
    __shared__ __align__(16) float lds_si[2048];             // 8 i-rows of Xp
    __shared__ __align__(16) float lds_bias1[128];
    __shared__ __align__(16) float lds_bias2[64];
    __shared__ __align__(16) float lds_w3[64];
    __shared__ float lds_c[2][8][33];

    const int tid = threadIdx.x;
    const int wave = tid >> 6;       // 0..7
    const int lane = tid & 63;
    const int hi = lane >> 5;        // 0/1: k-subgroup
    const int j32 = lane & 31;

    // grid decode: bx -> (b, br, it8, jt_a); 80 blocks per (b,br)
    int bx = blockIdx.x;
    int b = bx / 160;
    int r = bx - b * 160;
    int br = r / 80;
    int u = r - br * 80;
    int k = 0, off = 0;
    while (k < 7) {
        int cnt = 4 * ((9 - k) / 2);      // blocks in group k (4 it8's x ceil((8-k)/2))
        if (u < off + cnt) break;
        off += cnt; ++k;
    }
    int rel = u - off;
    int bpi = (9 - k) / 2;                // jt-pairs per it8 in this group
    int it8 = 4 * k + rel / bpi;          // 0..31
    int jt_a = k + 2 * (rel % bpi);       // first j-tile of this block

    const int i = it8 * 8 + wave;
    const int blk = br * 4 + b;
    const int jtA = jt_a;
    const bool validB = (jt_a + 1) < 8;
    const int jtB = validB ? jt_a + 1 : jt_a;   // clamp: duplicate work, writes masked

    // each wave stages its OWN si row (wave-internal, no barrier needed before use)
    *(float4*)&lds_si[wave * 256 + lane * 4] =
        *(const float4*)&Xp[((b * NR) + i) * CC + lane * 4];

    // stage full branch weights (80KB) + biases
    {
        const uint4* g1 = (const uint4*)(wpa + (size_t)br * 32768);
        uint4* s1 = (uint4*)lds_wa;
        #pragma unroll
        for (int kk = 0; kk < 8; ++kk) s1[kk * 512 + tid] = g1[kk * 512 + tid];
        const uint4* g2 = (const uint4*)(wpb + (size_t)br * 8192);
        uint4* s2 = (uint4*)lds_wb;
        #pragma unroll
        for (int kk = 0; kk < 2; ++kk) s2[kk * 512 + tid] = g2[kk * 512 + tid];
        if (tid < 128) lds_bias1[tid] = br ? b1[tid] : b01[tid];
        else if (tid < 192) lds_bias2[tid - 128] = br ? b2[tid - 128] : b02[tid - 128];
        else if (tid < 256) lds_w3[tid - 192] = br ? W3[tid - 192] : W03[tid - 192];
    }
    __syncthreads();
    const float b3v = br ? b3[0] : b03[0];
    const float* si = lds_si + wave * 256;

    // ---- build B-fragments of P^T for BOTH tiles: lane j, k = 16ks + 8hi + e ----
    const float* xrA = Xp + ((size_t)(b * NR) + (jtA * 32 + j32)) * CC;
    const float* xrB = Xp + ((size_t)(b * NR) + (jtB * 32 + j32)) * CC;
    short8 bfrA[16], bfrB[16];
    #pragma unroll
    for (int ks = 0; ks < 16; ++ks) {
        const int c0 = ks * 16 + hi * 8;
        float4 sa = *(const float4*)(si + c0);
        float4 sb = *(const float4*)(si + c0 + 4);
        {
            float4 xa = *(const float4*)(xrA + c0);
            float4 xb = *(const float4*)(xrA + c0 + 4);
            union { short8 s; unsigned int uu[4]; } f;
            f.uu[0] = pk2bf(xa.x * sa.x, xa.y * sa.y);
            f.uu[1] = pk2bf(xa.z * sa.z, xa.w * sa.w);
            f.uu[2] = pk2bf(xb.x * sb.x, xb.y * sb.y);
            f.uu[3] = pk2bf(xb.z * sb.z, xb.w * sb.w);
            bfrA[ks] = f.s;
        }
        {
            float4 xa = *(const float4*)(xrB + c0);
            float4 xb = *(const float4*)(xrB + c0 + 4);
            union { short8 s; unsigned int uu[4]; } f;
            f.uu[0] = pk2bf(xa.x * sa.x, xa.y * sa.y);
            f.uu[1] = pk2bf(xa.z * sa.z, xa.w * sa.w);
            f.uu[2] = pk2bf(xb.x * sb.x, xb.y * sb.y);
            f.uu[3] = pk2bf(xb.z * sb.z, xb.w * sb.w);
            bfrB[ks] = f.s;
        }
    }

    // ---- acc2 init (both tiles) ----
    f32x16 acc2A[2], acc2B[2];
    #pragma unroll
    for (int nt = 0; nt < 2; ++nt) {
        #pragma unroll
        for (int q = 0; q < 4; ++q) {
            const float* bb = &lds_bias2[nt * 32 + q * 8 + hi * 4];
            acc2A[nt][q * 4 + 0] = bb[0]; acc2B[nt][q * 4 + 0] = bb[0];
            acc2A[nt][q * 4 + 1] = bb[1]; acc2B[nt][q * 4 + 1] = bb[1];
            acc2A[nt][q * 4 + 2] = bb[2]; acc2B[nt][q * 4 + 2] = bb[2];
            acc2A[nt][q * 4 + 3] = bb[3]; acc2B[nt][q * 4 + 3] = bb[3];
        }
    }

    // ---- fused L1+L2, t-at-a-time; each wf/w2 LDS read feeds 2 MFMAs ----
    #pragma unroll 1
    for (int t = 0; t < 4; ++t) {
        f32x16 accA, accB;
        #pragma unroll
        for (int q = 0; q < 4; ++q) {
            const float* bb = &lds_bias1[t * 32 + q * 8 + hi * 4];
            accA[q * 4 + 0] = bb[0]; accB[q * 4 + 0] = bb[0];
            accA[q * 4 + 1] = bb[1]; accB[q * 4 + 1] = bb[1];
            accA[q * 4 + 2] = bb[2]; accB[q * 4 + 2] = bb[2];
            accA[q * 4 + 3] = bb[3]; accB[q * 4 + 3] = bb[3];
        }
        #pragma unroll
        for (int ks = 0; ks < 16; ++ks) {
            short8 wf = ((const short8*)lds_wa)[(t * 16 + ks) * 64 + lane];
            accA = __builtin_amdgcn_mfma_f32_32x32x16_bf16(wf, bfrA[ks], accA, 0, 0, 0);
            accB = __builtin_amdgcn_mfma_f32_32x32x16_bf16(wf, bfrB[ks], accB, 0, 0, 0);
        }
        #pragma unroll
        for (int s = 0; s < 2; ++s) {
            const int bse = s * 8;
            union { short8 s8; unsigned int uu[4]; } B2A, B2B;
            {
                float rA0 = fmaxf(accA[bse + 0], 0.f), rA1 = fmaxf(accA[bse + 1], 0.f);
                float rA2 = fmaxf(accA[bse + 2], 0.f), rA3 = fmaxf(accA[bse + 3], 0.f);
                float rB0 = fmaxf(accA[bse + 4], 0.f), rB1 = fmaxf(accA[bse + 5], 0.f);
                float rB2 = fmaxf(accA[bse + 6], 0.f), rB3 = fmaxf(accA[bse + 7], 0.f);
                unsigned int uA0 = pk2bf(rA0, rA1), uA1 = pk2bf(rA2, rA3);
                unsigned int uB0 = pk2bf(rB0, rB1), uB1 = pk2bf(rB2, rB3);
                unsigned int pA0 = __shfl_xor(uA0, 32, 64), pA1 = __shfl_xor(uA1, 32, 64);
                unsigned int pB0 = __shfl_xor(uB0, 32, 64), pB1 = __shfl_xor(uB1, 32, 64);
                B2A.uu[0] = hi ? pB0 : uA0;
                B2A.uu[1] = hi ? pB1 : uA1;
                B2A.uu[2] = hi ? uB0 : pA0;
                B2A.uu[3] = hi ? uB1 : pA1;
            }
            {
                float rA0 = fmaxf(accB[bse + 0], 0.f), rA1 = fmaxf(accB[bse + 1], 0.f);
                float rA2 = fmaxf(accB[bse + 2], 0.f), rA3 = fmaxf(accB[bse + 3], 0.f);
                float rB0 = fmaxf(accB[bse + 4], 0.f), rB1 = fmaxf(accB[bse + 5], 0.f);
                float rB2 = fmaxf(accB[bse + 6], 0.f), rB3 = fmaxf(accB[bse + 7], 0.f);
                unsigned int uA0 = pk2bf(rA0, rA1), uA1 = pk2bf(rA2, rA3);
                unsigned int uB0 = pk2bf(rB0, rB1), uB1 = pk2bf(rB2, rB3);
                unsigned int pA0 = __shfl_xor(uA0, 32, 64), pA1 = __shfl_xor(uA1, 32, 64);
                unsigned int pB0 = __shfl_xor(uB0, 32, 64), pB1 = __shfl_xor(uB1, 32, 64);
                B2B.uu[0] = hi ? pB0 : uA0;
                B2B.uu[1] = hi ? pB1 : uA1;
                B2B.uu[2] = hi ? uB0 : pA0;
                B2B.uu[3] = hi ? uB1 : pA1;
            }
            const int ks2 = 2 * t + s;
            short8 w20 = ((const short8*)lds_wb)[ks2 * 64 + lane];
            short8 w21 = ((const short8*)lds_wb)[(8 + ks2) * 64 + lane];
            acc2A[0] = __builtin_amdgcn_mfma_f32_32x32x16_bf16(w20, B2A.s8, acc2A[0], 0, 0, 0);
            acc2B[0] = __builtin_amdgcn_mfma_f32_32x32x16_bf16(w20, B2B.s8, acc2B[0], 0, 0, 0);
            acc2A[1] = __builtin_amdgcn_mfma_f32_32x32x16_bf16(w21, B2A.s8, acc2A[1], 0, 0, 0);
            acc2B[1] = __builtin_amdgcn_mfma_f32_32x32x16_bf16(w21, B2B.s8, acc2B[1], 0, 0, 0);
        }
    }

    // ---- layer 3 (both tiles) ----
    float partA = 0.f, partB = 0.f;
    #pragma unroll
    for (int nt = 0; nt < 2; ++nt) {
        #pragma unroll
        for (int q = 0; q < 4; ++q) {
            const float* wv = &lds_w3[nt * 32 + q * 8 + hi * 4];
            partA += fmaxf(acc2A[nt][q * 4 + 0], 0.f) * wv[0];
            partA += fmaxf(acc2A[nt][q * 4 + 1], 0.f) * wv[1];
            partA += fmaxf(acc2A[nt][q * 4 + 2], 0.f) * wv[2];
            partA += fmaxf(acc2A[nt][q * 4 + 3], 0.f) * wv[3];
            partB += fmaxf(acc2B[nt][q * 4 + 0], 0.f) * wv[0];
            partB += fmaxf(acc2B[nt][q * 4 + 1], 0.f) * wv[1];
            partB += fmaxf(acc2B[nt][q * 4 + 2], 0.f) * wv[2];
            partB += fmaxf(acc2B[nt][q * 4 + 3], 0.f) * wv[3];
        }
    }
    partA += __shfl_xor(partA, 32, 64);
    partB += __shfl_xor(partB, 32, 64);
    const float hA = fmaxf(partA + b3v, 0.f);
    const float hB = fmaxf(partB + b3v, 0.f);
    const float EA = __expf(2.f * hA);
    const float EB = __expf(2.f * hB);
    const int jA = jtA * 32 + j32;
    const int jB = jtB * 32 + j32;
    const float EcA = (jA >= i) ? EA : 0.f;
    const float EcB = (validB && jB >= i) ? EB : 0.f;
    float ErA = (jA > i) ? EA : 0.f;
    float ErB = (validB && jB > i) ? EB : 0.f;

    #pragma unroll
    for (int sh = 1; sh <= 32; sh <<= 1) {
        ErA += __shfl_xor(ErA, sh, 64);
        ErB += __shfl_xor(ErB, sh, 64);
    }
    if (lane == 0) {
        rowpart[((size_t)blk * NR + i) * 8 + jtA] = 0.5f * ErA;
        if (validB) rowpart[((size_t)blk * NR + i) * 8 + jtB] = 0.5f * ErB;
    }

    if (!hi) {
        lds_c[0][wave][j32] = EcA;
        lds_c[1][wave][j32] = EcB;
    }
    __syncthreads();
    if (tid < 64) {
        int tile = tid >> 5, col = tid & 31;
        if (tile == 0 || validB) {
            float c = 0.f;
            #pragma unroll
            for (int w2 = 0; w2 < 8; ++w2) c += lds_c[tile][w2][col];
            int jt = tile ? jtB : jtA;
            colpart[(size_t)blk * 4608 + 64 * jt * (jt + 1) + col * (4 * jt + 4) + it8] = c;
        }
    }
}

// ---------------- colsum[j] = ragged colpart + rowpart (symmetry); wn = colsum/Z ----------------
__global__ __launch_bounds__(256) void colsoft_final_kernel(
    const float* __restrict__ colpart, const float* __restrict__ rowpart,
    float* __restrict__ wn)
{
    const int blk = blockIdx.x;        // 0..7 = br*4+b
    const int j = threadIdx.x;
    const int jt = j >> 5, j32l = j & 31;
    const int cnt = 4 * jt + 4;
    float cs = 0.f;
    const float* cp = colpart + (size_t)blk * 4608 + 64 * jt * (jt + 1) + j32l * cnt;
    for (int it2 = 0; it2 < cnt; ++it2) cs += cp[it2];
    const float* rp = rowpart + ((size_t)blk * NR + j) * 8;
    for (int q = jt; q < 8; ++q) cs += rp[q];

    __shared__ float red[256];
    red[j] = cs; __syncthreads();
    for (int s = 128; s > 0; s >>= 1) {
        if (j < s) red[j] += red[j + s];
        __syncthreads();
    }
    wn[blk * 256 + j] = cs / red[0];
}

// ---------------- agg stage 1: partial weighted sums over j-chunks ----------------
__global__ __launch_bounds__(256) void agg_part_kernel(
    const float* __restrict__ X, const float* __restrict__ wn,
    float* __restrict__ apart)
{
    const int dc = blockIdx.x, b = blockIdx.y, jc = blockIdx.z;
    const int d = dc * 256 + threadIdx.x;
    __shared__ float wc[32];
    if (threadIdx.x < 32) {
        int j = jc * 32 + threadIdx.x;
        wc[threadIdx.x] = 0.5f * (wn[b * 256 + j] + wn[(4 + b) * 256 + j]);
    }
    __syncthreads();
    if (d < 2052) {
        const float* xp = X + (size_t)b * NR * 2052 + (size_t)jc * 32 * 2052 + d;
        float a0 = 0.f, a1 = 0.f, a2 = 0.f, a3 = 0.f;
        for (int rr = 0; rr < 32; rr += 4) {
            a0 += wc[rr + 0] * xp[(size_t)(rr + 0) * 2052];
            a1 += wc[rr + 1] * xp[(size_t)(rr + 1) * 2052];
            a2 += wc[rr + 2] * xp[(size_t)(rr + 2) * 2052];
            a3 += wc[rr + 3] * xp[(size_t)(rr + 3) * 2052];
        }
        apart[(size_t)(jc * 4 + b) * 2304 + d] = (a0 + a1) + (a2 + a3);
    }
}

// ---------------- agg stage 2: sum partials ----------------
__global__ __launch_bounds__(256) void agg_final_kernel(
    const float* __restrict__ apart, float* __restrict__ out)
{
    const int dc = blockIdx.x, b = blockIdx.y;
    const int d = dc * 256 + threadIdx.x;
    if (d < 2052) {
        float s = 0.f;
        #pragma unroll
        for (int jc = 0; jc < 8; ++jc) s += apart[(size_t)(jc * 4 + b) * 2304 + d];
        out[b * 2052 + d] = s;
    }
}

extern "C" void kernel_launch(void* const* d_in, const int* in_sizes, int n_in,
                              void* d_out, int out_size, void* d_ws, size_t ws_size,
                              hipStream_t stream) {
    const float* Q   = (const float*)d_in[0];
    const float* X   = (const float*)d_in[1];
    const float* Wv  = (const float*)d_in[2];
    const float* bv  = (const float*)d_in[3];
    const float* Wq  = (const float*)d_in[4];
    const float* bq  = (const float*)d_in[5];
    const float* W01 = (const float*)d_in[6];
    const float* b01 = (const float*)d_in[7];
    const float* W02 = (const float*)d_in[8];
    const float* b02 = (const float*)d_in[9];
    const float* W03 = (const float*)d_in[10];
    const float* b03 = (const float*)d_in[11];
    const float* W1  = (const float*)d_in[12];
    const float* b1  = (const float*)d_in[13];
    const float* W2  = (const float*)d_in[14];
    const float* b2  = (const float*)d_in[15];
    const float* W3  = (const float*)d_in[16];
    const float* b3  = (const float*)d_in[17];

    char* ws = (char*)d_ws;
    // layout; aliases: wvp over colpart/rowpart region (dead before pairs writes),
    // apart over Xp (dead after pairs)
    float* Xp   = (float*)(ws + 0);              // 1,048,576 B
    float* Qpp  = (float*)(ws + 1048576);        //    16,384 B
    float* wn   = (float*)(ws + 1064960);        //     8,192 B
    unsigned short* wpa = (unsigned short*)(ws + 1073152);  // 131,072 B
    unsigned short* wpb = (unsigned short*)(ws + 1204224);  //  32,768 B
    float* colpart = (float*)(ws + 1236992);     // 147,456 B  [8][4608] ragged
    float* rowpart = (float*)(ws + 1384448);     //  65,536 B  [8][256][8] -> end 1,449,984
    unsigned short* wvp = (unsigned short*)(ws + 1236992);  // 1,064,960 B (aliased, ends 2,301,952)
    float* apart = (float*)(ws + 0);             // 294,912 B (aliases Xp)
    float* out = (float*)d_out;

    setup_kernel<<<401, 256, 0, stream>>>(Q, Wq, Qpp, Wv, wvp,
                                          W01, W1, W02, W2, wpa, wpb);
    xp_kernel<<<dim3(16, 8, 4), 512, 0, stream>>>(X, wvp, bv, bq, Qpp, Xp);
    pairs_kernel<<<640, 512, 0, stream>>>(Xp, wpa, wpb, b01, b02, b03,
                                          b1, b2, b3, W03, W3, colpart, rowpart);
    colsoft_final_kernel<<<8, 256, 0, stream>>>(colpart, rowpart, wn);
    agg_part_kernel<<<dim3(9, 4, 8), 256, 0, stream>>>(X, wn, apart);
    agg_final_kernel<<<dim3(9, 4), 256, 0, stream>>>(apart, out);
}

// Round 11
// 91.801 us; speedup vs baseline: 1.2371x; 1.2371x over previous
//
#include <hip/hip_runtime.h>
#include <hip/hip_bf16.h>

typedef __attribute__((ext_vector_type(8)))  short short8;
typedef __attribute__((ext_vector_type(4)))  float f32x4;
typedef __attribute__((ext_vector_type(16))) float f32x16;

#define NR 256
#define CC 256

__device__ __forceinline__ unsigned short f2bf(float x) {
    union { float f; unsigned int u; } v; v.f = x;
    unsigned int r = v.u + 0x7FFFu + ((v.u >> 16) & 1u);
    return (unsigned short)(r >> 16);
}

__device__ __forceinline__ unsigned int pk2bf(float a, float b) {
    __hip_bfloat162 h = __float22bfloat162_rn(make_float2(a, b));
    union { __hip_bfloat162 h; unsigned int u; } cv; cv.h = h;
    return cv.u;
}

// ---------------- setup: qp (bx<16) | wvp_pack (bx<81) | mlp pack (else) ----------------
__global__ __launch_bounds__(256) void setup_kernel(
    const float* __restrict__ Q, const float* __restrict__ Wq, float* __restrict__ Qpp,
    const float* __restrict__ Wv, unsigned short* __restrict__ wvp,
    const float* __restrict__ W01, const float* __restrict__ W1,
    const float* __restrict__ W02, const float* __restrict__ W2,
    unsigned short* __restrict__ wpa, unsigned short* __restrict__ wpb)
{
    __shared__ float tile[32][260];
    __shared__ float qs[256];
    const int bx = blockIdx.x;
    const int tid = threadIdx.x;

    if (bx < 16) {                       // ---- Qpp[ksl][b][n] = partial Q @ Wq
        int ksl = bx & 3, b = bx >> 2;
        qs[tid] = Q[b * 1024 + ksl * 256 + tid];
        __syncthreads();
        float acc = 0.f;
        #pragma unroll 4
        for (int d = 0; d < 256; ++d) acc += qs[d] * Wq[(size_t)(ksl * 256 + d) * 256 + tid];
        Qpp[(ksl * 4 + b) * 256 + tid] = acc;
    } else if (bx < 81) {                // ---- Wv -> 16x16x32 B-frag layout, K pad 2080
        int ks = bx - 16;                // 0..64
        for (int idx = tid; idx < 32 * 256; idx += 256) {
            int cr = idx >> 8, n = idx & 255;
            int c = ks * 32 + cr;
            tile[cr][n] = (c < 2056) ? Wv[(size_t)c * 256 + n] : 0.f;
        }
        __syncthreads();
        #pragma unroll
        for (int q = 0; q < 4; ++q) {
            int t2 = tid * 4 + q;
            int nt = t2 >> 6, l = t2 & 63;
            int gg = l >> 4, jj = l & 15;
            short8 s;
            #pragma unroll
            for (int e = 0; e < 8; ++e)
                s[e] = (short)f2bf(tile[gg * 8 + e][nt * 16 + jj]);
            *(short8*)&wvp[((size_t)(ks * 16 + nt) * 64 + l) * 8] = s;
        }
    } else {                             // ---- MLP weights -> 32x32x16 A-frag layout
        int t = (bx - 81) * 256 + tid;   // < 81920
        if (t < 65536) {
            int e = t & 7, l = (t >> 3) & 63, ks = (t >> 9) & 15, nt = (t >> 13) & 3, br = (t >> 15) & 1;
            int cc = ks * 16 + (l >> 5) * 8 + e;
            int n = nt * 32 + (l & 31);
            const float* W = br ? W1 : W01;
            wpa[t] = f2bf(W[cc * 128 + n]);
        } else {
            int t2 = t - 65536;          // < 16384
            int e = t2 & 7, l = (t2 >> 3) & 63, ks = (t2 >> 9) & 7, nt = (t2 >> 12) & 1, br = (t2 >> 13) & 1;
            int cc = ks * 16 + (l >> 5) * 8 + e;
            int n = nt * 32 + (l & 31);
            const float* W = br ? W2 : W02;
            wpb[t2] = f2bf(W[cc * 64 + n]);
        }
    }
}

// ---------------- Xp = concat(X, X[:,:,:4]) @ Wv + bv + bq + Qp  (MFMA, 8-wave split-K) ----------------
__global__ __launch_bounds__(512) void xp_kernel(
    const float* __restrict__ X, const unsigned short* __restrict__ wvp,
    const float* __restrict__ bv, const float* __restrict__ bq,
    const float* __restrict__ Qpp, float* __restrict__ Xp)
{
    __shared__ f32x4 red[8][2][65];
    const int tid = threadIdx.x;
    const int w = tid >> 6;           // 0..7
    const int lane = tid & 63;
    const int g = lane >> 4, j16 = lane & 15;
    const int mt = blockIdx.x;        // 16-row tile
    const int bn = blockIdx.y;        // 32-col tile (0..7)
    const int b  = blockIdx.z;

    const int i0 = mt * 16;
    const int n0 = bn * 32;
    const float* xrow = X + ((size_t)(b * NR) + (i0 + j16)) * 2052;

    f32x4 acc[2] = {};

    for (int ks = w; ks < 64; ks += 8) {
        const int c0 = ks * 32 + g * 8;
        float4 xa = *(const float4*)(xrow + c0);
        float4 xb = *(const float4*)(xrow + c0 + 4);
        union { short8 s; unsigned int u[4]; } af;
        af.u[0] = pk2bf(xa.x, xa.y);
        af.u[1] = pk2bf(xa.z, xa.w);
        af.u[2] = pk2bf(xb.x, xb.y);
        af.u[3] = pk2bf(xb.z, xb.w);
        #pragma unroll
        for (int nt = 0; nt < 2; ++nt) {
            short8 bf = ((const short8*)wvp)[(size_t)(ks * 16 + bn * 2 + nt) * 64 + lane];
            acc[nt] = __builtin_amdgcn_mfma_f32_16x16x32_bf16(af.s, bf, acc[nt], 0, 0, 0);
        }
    }
    if (w == 0) {  // ks = 64 tail: c 2048..2079 (c>=2056 zero-weighted)
        float xv[8];
        #pragma unroll
        for (int e = 0; e < 8; ++e) {
            int q = g * 8 + e;
            int csrc = (q < 4) ? (2048 + q) : (q - 4);
            xv[e] = xrow[csrc];
        }
        union { short8 s; unsigned int u[4]; } af;
        af.u[0] = pk2bf(xv[0], xv[1]);
        af.u[1] = pk2bf(xv[2], xv[3]);
        af.u[2] = pk2bf(xv[4], xv[5]);
        af.u[3] = pk2bf(xv[6], xv[7]);
        #pragma unroll
        for (int nt = 0; nt < 2; ++nt) {
            short8 bf = ((const short8*)wvp)[(size_t)(64 * 16 + bn * 2 + nt) * 64 + lane];
            acc[nt] = __builtin_amdgcn_mfma_f32_16x16x32_bf16(af.s, bf, acc[nt], 0, 0, 0);
        }
    }
    #pragma unroll
    for (int nt = 0; nt < 2; ++nt) red[w][nt][lane] = acc[nt];
    __syncthreads();

    {   // 512 threads, one output each: 16 rows x 32 cols
        int nt  = tid >> 8;              // 0..1
        int rem = tid & 255;
        int l   = rem & 63;
        int reg = (rem >> 6) & 3;
        float r = 0.f;
        #pragma unroll
        for (int ww = 0; ww < 8; ++ww) r += red[ww][nt][l][reg];
        int gg = l >> 4, jj = l & 15;
        int n = n0 + nt * 16 + jj;
        float base = bv[n] + bq[n] + Qpp[b * 256 + n] + Qpp[(4 + b) * 256 + n]
                   + Qpp[(8 + b) * 256 + n] + Qpp[(12 + b) * 256 + n];
        int row = i0 + gg * 4 + reg;
        Xp[((b * NR) + row) * CC + n] = r + base;
    }
}

// ---------------- fused 3-layer MLP over pairs: 8-wave, W1-in-LDS, W2-in-regs, 2 blocks/CU ----------------
// block = (b, br, it8 in [0,32), ONE jt in [it8/4, 8)). 1152 blocks.
// r10 lesson: halving LDS weight reads was NULL -> DS BW is not the wall; the flat
// ~8.4K cyc/wave-tile across r5/r7/r9/r10 at 2 waves/SIMD is exposed LATENCY.
// Fix: occupancy. LDS trimmed 93.7->75.8 KB (W2 evicted to a 16-frag register load
// issued AFTER L1, where bfr dies -> no VGPR peak growth) => 2 blocks/CU, 16 waves/CU,
// 4 waves/SIMD. __launch_bounds__(512,2): cap 128 (r9 used 92; proven regime).
__global__ __launch_bounds__(512, 2) void pairs_kernel(
    const float* __restrict__ Xp,
    const unsigned short* __restrict__ wpa,
    const unsigned short* __restrict__ wpb,
    const float* __restrict__ b01, const float* __restrict__ b02,
    const float* __restrict__ b03,
    const float* __restrict__ b1,  const float* __restrict__ b2,
    const float* __restrict__ b3,
    const float* __restrict__ W03, const float* __restrict__ W3,
    float* __restrict__ colpart, float* __restrict__ rowpart)
{
    __shared__ __align__(16) unsigned short lds_wa[32768];   // 64 KB: FULL W1 frags (this branch)
    __shared__ __align__(16) float lds_si[2048];             // 8 i-rows of Xp
    __shared__ __align__(16) float lds_bias1[128];
    __shared__ __align__(16) float lds_bias2[64];
    __shared__ __align__(16) float lds_w3[64];
    __shared__ float lds_c[8][33];

    const int tid = threadIdx.x;
    const int wave = tid >> 6;       // 0..7
    const int lane = tid & 63;
    const int hi = lane >> 5;        // 0/1: k-subgroup
    const int j32 = lane & 31;

    // grid decode: bx -> (b, br, it8, jt); 144 tiles per (b,br)
    int bx = blockIdx.x;
    int b = bx / 288;
    int r = bx - b * 288;
    int br = r / 144;
    int u = r - br * 144;
    int k = 0, off = 0;
    while (k < 7) {
        int cnt = 4 * (8 - k);            // blocks in group k
        if (u < off + cnt) break;
        off += cnt; ++k;
    }
    int rel = u - off;
    int it8 = 4 * k + rel / (8 - k);      // 0..31
    int jt  = k + rel % (8 - k);          // it8/4 .. 7

    const int i = it8 * 8 + wave;
    const int blk = br * 4 + b;
    const int j0 = jt * 32;
    const int j = j0 + j32;

    // each wave stages its OWN si row (wave-internal, no barrier needed before use)
    *(float4*)&lds_si[wave * 256 + lane * 4] =
        *(const float4*)&Xp[((b * NR) + i) * CC + lane * 4];

    // stage full branch W1 (64KB) + biases
    {
        const uint4* g1 = (const uint4*)(wpa + (size_t)br * 32768);
        uint4* s1 = (uint4*)lds_wa;
        #pragma unroll
        for (int kk = 0; kk < 8; ++kk) s1[kk * 512 + tid] = g1[kk * 512 + tid];
        if (tid < 128) lds_bias1[tid] = br ? b1[tid] : b01[tid];
        else if (tid < 192) lds_bias2[tid - 128] = br ? b2[tid - 128] : b02[tid - 128];
        else if (tid < 256) lds_w3[tid - 192] = br ? W3[tid - 192] : W03[tid - 192];
    }
    __syncthreads();
    const float b3v = br ? b3[0] : b03[0];
    const float* si = lds_si + wave * 256;

    // ---- build B-fragments of P^T: lane j, k = 16ks + 8hi + e ----
    const float* xr = Xp + ((size_t)(b * NR) + j) * CC;
    short8 bfr[16];
    #pragma unroll
    for (int ks = 0; ks < 16; ++ks) {
        const int c0 = ks * 16 + hi * 8;
        float4 xa = *(const float4*)(xr + c0);
        float4 xb = *(const float4*)(xr + c0 + 4);
        float4 sa = *(const float4*)(si + c0);
        float4 sb = *(const float4*)(si + c0 + 4);
        union { short8 s; unsigned int uu[4]; } f;
        f.uu[0] = pk2bf(xa.x * sa.x, xa.y * sa.y);
        f.uu[1] = pk2bf(xa.z * sa.z, xa.w * sa.w);
        f.uu[2] = pk2bf(xb.x * sb.x, xb.y * sb.y);
        f.uu[3] = pk2bf(xb.z * sb.z, xb.w * sb.w);
        bfr[ks] = f.s;
    }

    // ---- layer 1: ks-outer / t-inner -> 4 independent MFMA chains, W1 from LDS ----
    f32x16 acc1[4];
    #pragma unroll
    for (int t = 0; t < 4; ++t) {
        #pragma unroll
        for (int q = 0; q < 4; ++q) {
            const float* bb = &lds_bias1[t * 32 + q * 8 + hi * 4];
            acc1[t][q * 4 + 0] = bb[0];
            acc1[t][q * 4 + 1] = bb[1];
            acc1[t][q * 4 + 2] = bb[2];
            acc1[t][q * 4 + 3] = bb[3];
        }
    }
    #pragma unroll
    for (int ks = 0; ks < 16; ++ks) {
        const short8 bb = bfr[ks];
        #pragma unroll
        for (int t = 0; t < 4; ++t) {
            short8 wf = ((const short8*)lds_wa)[(t * 16 + ks) * 64 + lane];
            acc1[t] = __builtin_amdgcn_mfma_f32_32x32x16_bf16(wf, bb, acc1[t], 0, 0, 0);
        }
    }

    // ---- W2 fragments: 16 batched loads from L2 into regs (bfr is dead now) ----
    short8 w2r[16];
    {
        const short8* wb = (const short8*)wpb + (size_t)br * 1024;
        #pragma unroll
        for (int q = 0; q < 16; ++q) w2r[q] = wb[q * 64 + lane];
    }

    // ---- layer 2: relu + pack + lane^32 exchange; 2 alternating acc2 chains ----
    f32x16 acc2[2];
    #pragma unroll
    for (int nt = 0; nt < 2; ++nt) {
        #pragma unroll
        for (int q = 0; q < 4; ++q) {
            const float* bb = &lds_bias2[nt * 32 + q * 8 + hi * 4];
            acc2[nt][q * 4 + 0] = bb[0];
            acc2[nt][q * 4 + 1] = bb[1];
            acc2[nt][q * 4 + 2] = bb[2];
            acc2[nt][q * 4 + 3] = bb[3];
        }
    }
    #pragma unroll
    for (int t = 0; t < 4; ++t) {
        #pragma unroll
        for (int s = 0; s < 2; ++s) {
            const int bse = s * 8;
            float rA0 = fmaxf(acc1[t][bse + 0], 0.f), rA1 = fmaxf(acc1[t][bse + 1], 0.f);
            float rA2 = fmaxf(acc1[t][bse + 2], 0.f), rA3 = fmaxf(acc1[t][bse + 3], 0.f);
            float rB0 = fmaxf(acc1[t][bse + 4], 0.f), rB1 = fmaxf(acc1[t][bse + 5], 0.f);
            float rB2 = fmaxf(acc1[t][bse + 6], 0.f), rB3 = fmaxf(acc1[t][bse + 7], 0.f);
            unsigned int uA0 = pk2bf(rA0, rA1), uA1 = pk2bf(rA2, rA3);
            unsigned int uB0 = pk2bf(rB0, rB1), uB1 = pk2bf(rB2, rB3);
            unsigned int pA0 = __shfl_xor(uA0, 32, 64), pA1 = __shfl_xor(uA1, 32, 64);
            unsigned int pB0 = __shfl_xor(uB0, 32, 64), pB1 = __shfl_xor(uB1, 32, 64);
            union { short8 s8; unsigned int uu[4]; } B2;
            B2.uu[0] = hi ? pB0 : uA0;
            B2.uu[1] = hi ? pB1 : uA1;
            B2.uu[2] = hi ? uB0 : pA0;
            B2.uu[3] = hi ? uB1 : pA1;
            const int ks2 = 2 * t + s;
            acc2[0] = __builtin_amdgcn_mfma_f32_32x32x16_bf16(w2r[ks2], B2.s8, acc2[0], 0, 0, 0);
            acc2[1] = __builtin_amdgcn_mfma_f32_32x32x16_bf16(w2r[8 + ks2], B2.s8, acc2[1], 0, 0, 0);
        }
    }

    // ---- layer 3: per-lane partial dot, reduce across hi pair ----
    float part = 0.f;
    #pragma unroll
    for (int nt = 0; nt < 2; ++nt) {
        #pragma unroll
        for (int q = 0; q < 4; ++q) {
            const float* wv = &lds_w3[nt * 32 + q * 8 + hi * 4];
            part += fmaxf(acc2[nt][q * 4 + 0], 0.f) * wv[0];
            part += fmaxf(acc2[nt][q * 4 + 1], 0.f) * wv[1];
            part += fmaxf(acc2[nt][q * 4 + 2], 0.f) * wv[2];
            part += fmaxf(acc2[nt][q * 4 + 3], 0.f) * wv[3];
        }
    }
    part += __shfl_xor(part, 32, 64);
    const float h3 = fmaxf(part + b3v, 0.f);
    const float E = __expf(2.f * h3);
    const float Ec = (j >= i) ? E : 0.f;      // col contribution (incl diag)
    float Er = (j >  i) ? E : 0.f;            // row contribution (strict upper)

    Er += __shfl_xor(Er, 1, 64);
    Er += __shfl_xor(Er, 2, 64);
    Er += __shfl_xor(Er, 4, 64);
    Er += __shfl_xor(Er, 8, 64);
    Er += __shfl_xor(Er, 16, 64);
    Er += __shfl_xor(Er, 32, 64);             // duplicated hi halves -> 2x row sum
    if (lane == 0)
        rowpart[((size_t)blk * NR + i) * 8 + jt] = 0.5f * Er;

    if (!hi) lds_c[wave][j32] = Ec;
    __syncthreads();
    if (tid < 32) {
        float c = 0.f;
        #pragma unroll
        for (int w2 = 0; w2 < 8; ++w2) c += lds_c[w2][tid];
        // ragged colpart: per (j, it8) slot; valid it8 count for tile jt = 4jt+4
        colpart[(size_t)blk * 4608 + 64 * jt * (jt + 1) + tid * (4 * jt + 4) + it8] = c;
    }
}

// ---------------- colsum[j] = ragged colpart + rowpart (symmetry); wn = colsum/Z ----------------
__global__ __launch_bounds__(256) void colsoft_final_kernel(
    const float* __restrict__ colpart, const float* __restrict__ rowpart,
    float* __restrict__ wn)
{
    const int blk = blockIdx.x;        // 0..7 = br*4+b
    const int j = threadIdx.x;
    const int jt = j >> 5, j32l = j & 31;
    const int cnt = 4 * jt + 4;
    float cs = 0.f;
    const float* cp = colpart + (size_t)blk * 4608 + 64 * jt * (jt + 1) + j32l * cnt;
    for (int it2 = 0; it2 < cnt; ++it2) cs += cp[it2];
    const float* rp = rowpart + ((size_t)blk * NR + j) * 8;
    for (int q = jt; q < 8; ++q) cs += rp[q];

    __shared__ float red[256];
    red[j] = cs; __syncthreads();
    for (int s = 128; s > 0; s >>= 1) {
        if (j < s) red[j] += red[j + s];
        __syncthreads();
    }
    wn[blk * 256 + j] = cs / red[0];
}

// ---------------- agg stage 1: partial weighted sums over j-chunks ----------------
__global__ __launch_bounds__(256) void agg_part_kernel(
    const float* __restrict__ X, const float* __restrict__ wn,
    float* __restrict__ apart)
{
    const int dc = blockIdx.x, b = blockIdx.y, jc = blockIdx.z;
    const int d = dc * 256 + threadIdx.x;
    __shared__ float wc[32];
    if (threadIdx.x < 32) {
        int j = jc * 32 + threadIdx.x;
        wc[threadIdx.x] = 0.5f * (wn[b * 256 + j] + wn[(4 + b) * 256 + j]);
    }
    __syncthreads();
    if (d < 2052) {
        const float* xp = X + (size_t)b * NR * 2052 + (size_t)jc * 32 * 2052 + d;
        float a0 = 0.f, a1 = 0.f, a2 = 0.f, a3 = 0.f;
        for (int rr = 0; rr < 32; rr += 4) {
            a0 += wc[rr + 0] * xp[(size_t)(rr + 0) * 2052];
            a1 += wc[rr + 1] * xp[(size_t)(rr + 1) * 2052];
            a2 += wc[rr + 2] * xp[(size_t)(rr + 2) * 2052];
            a3 += wc[rr + 3] * xp[(size_t)(rr + 3) * 2052];
        }
        apart[(size_t)(jc * 4 + b) * 2304 + d] = (a0 + a1) + (a2 + a3);
    }
}

// ---------------- agg stage 2: sum partials ----------------
__global__ __launch_bounds__(256) void agg_final_kernel(
    const float* __restrict__ apart, float* __restrict__ out)
{
    const int dc = blockIdx.x, b = blockIdx.y;
    const int d = dc * 256 + threadIdx.x;
    if (d < 2052) {
        float s = 0.f;
        #pragma unroll
        for (int jc = 0; jc < 8; ++jc) s += apart[(size_t)(jc * 4 + b) * 2304 + d];
        out[b * 2052 + d] = s;
    }
}

extern "C" void kernel_launch(void* const* d_in, const int* in_sizes, int n_in,
                              void* d_out, int out_size, void* d_ws, size_t ws_size,
                              hipStream_t stream) {
    const float* Q   = (const float*)d_in[0];
    const float* X   = (const float*)d_in[1];
    const float* Wv  = (const float*)d_in[2];
    const float* bv  = (const float*)d_in[3];
    const float* Wq  = (const float*)d_in[4];
    const float* bq  = (const float*)d_in[5];
    const float* W01 = (const float*)d_in[6];
    const float* b01 = (const float*)d_in[7];
    const float* W02 = (const float*)d_in[8];
    const float* b02 = (const float*)d_in[9];
    const float* W03 = (const float*)d_in[10];
    const float* b03 = (const float*)d_in[11];
    const float* W1  = (const float*)d_in[12];
    const float* b1  = (const float*)d_in[13];
    const float* W2  = (const float*)d_in[14];
    const float* b2  = (const float*)d_in[15];
    const float* W3  = (const float*)d_in[16];
    const float* b3  = (const float*)d_in[17];

    char* ws = (char*)d_ws;
    // layout; aliases: wvp over colpart/rowpart region (dead before pairs writes),
    // apart over Xp (dead after pairs)
    float* Xp   = (float*)(ws + 0);              // 1,048,576 B
    float* Qpp  = (float*)(ws + 1048576);        //    16,384 B
    float* wn   = (float*)(ws + 1064960);        //     8,192 B
    unsigned short* wpa = (unsigned short*)(ws + 1073152);  // 131,072 B
    unsigned short* wpb = (unsigned short*)(ws + 1204224);  //  32,768 B
    float* colpart = (float*)(ws + 1236992);     // 147,456 B  [8][4608] ragged
    float* rowpart = (float*)(ws + 1384448);     //  65,536 B  [8][256][8] -> end 1,449,984
    unsigned short* wvp = (unsigned short*)(ws + 1236992);  // 1,064,960 B (aliased, ends 2,301,952)
    float* apart = (float*)(ws + 0);             // 294,912 B (aliases Xp)
    float* out = (float*)d_out;

    setup_kernel<<<401, 256, 0, stream>>>(Q, Wq, Qpp, Wv, wvp,
                                          W01, W1, W02, W2, wpa, wpb);
    xp_kernel<<<dim3(16, 8, 4), 512, 0, stream>>>(X, wvp, bv, bq, Qpp, Xp);
    pairs_kernel<<<1152, 512, 0, stream>>>(Xp, wpa, wpb, b01, b02, b03,
                                           b1, b2, b3, W03, W3, colpart, rowpart);
    colsoft_final_kernel<<<8, 256, 0, stream>>>(colpart, rowpart, wn);
    agg_part_kernel<<<dim3(9, 4, 8), 256, 0, stream>>>(X, wn, apart);
    agg_final_kernel<<<dim3(9, 4), 256, 0, stream>>>(apart, out);
}